// Round 17
// baseline (200.486 us; speedup 1.0000x reference)
//
#include <hip/hip_runtime.h>
#include <math.h>

#define T_ 243
#define P_ 17
#define L_ 4
#define C_ 128
#define H_ 8
#define NPTS_ 4
#define DH_ 16
#define B_ 2
#define LQ (T_*P_*L_)      /* 16524 */
#define NT1 (B_*LQ)        /* 33048 */
#define LL (L_+1)          /* 5 */
#define S_ (P_*LL)         /* 85 */
#define NT2 (B_*T_*P_*LL)  /* 41310 */

typedef __attribute__((ext_vector_type(8))) short short8v;
typedef __attribute__((ext_vector_type(4))) short short4v;
typedef __attribute__((ext_vector_type(4))) float float4v;

#if defined(__has_builtin)
# if __has_builtin(__builtin_amdgcn_mfma_f32_16x16x16bf16_1k)
#  define HAVE_M16 1
# endif
#endif

__device__ __forceinline__ unsigned short f2bf(float f){
  union { float f; unsigned u; } un; un.f = f;
  unsigned r = un.u + 0x7FFF + ((un.u >> 16) & 1);   // RNE
  return (unsigned short)(r >> 16);
}
__device__ __forceinline__ float bf2f(unsigned short u){
  union { unsigned u; float f; } un; un.u = ((unsigned)u) << 16; return un.f;
}
// async global->LDS DMA, 16B per lane; dest = wave-uniform base + lane*16 (linear).
// One call covers 4 rows x 16 chunks of a 256B/row tile: row = rb + (lane>>4), chunk = lane&15.
__device__ __forceinline__ void dma16(const unsigned short* g, unsigned short* l){
  __builtin_amdgcn_global_load_lds(
      (const __attribute__((address_space(1))) void*)g,
      (__attribute__((address_space(3))) void*)l, 16, 0, 0);
}

// ---------------- weight convert fp32 -> bf16, layout preserved [N][K] ----------------
__global__ void k_wcvt(const float* __restrict__ w0, const float* __restrict__ w1,
                       const float* __restrict__ w2, const float* __restrict__ w3,
                       const float* __restrict__ w4, const float* __restrict__ w5,
                       const float* __restrict__ w6, const float* __restrict__ w7,
                       unsigned short* __restrict__ dst){
  int i = blockIdx.x*256 + threadIdx.x;
  if (i >= 278528) return;
  float v;
  if      (i < 32768)  v = w0[i];
  else if (i < 49152)  v = w1[i-32768];
  else if (i < 65536)  v = w2[i-49152];
  else if (i < 81920)  v = w3[i-65536];
  else if (i < 131072) v = w4[i-81920];
  else if (i < 147456) v = w5[i-131072];
  else if (i < 212992) v = w6[i-147456];
  else                 v = w7[i-212992];
  dst[i] = f2bf(v);
}

// ---------------- LN1 + q (lv1..4 rows) AND x0-row copy+LN2 (merged) ----------------
__global__ __launch_bounds__(256) void k_ln1_q(
    const float* __restrict__ x, const float* __restrict__ pe,
    const float* __restrict__ lpos, const float* __restrict__ g1,
    const float* __restrict__ be1, const float* __restrict__ g2,
    const float* __restrict__ be2, unsigned short* __restrict__ xn,
    unsigned short* __restrict__ q, float* __restrict__ xcat,
    unsigned short* __restrict__ xn2) {
  int w = threadIdx.x >> 6; int lane = threadIdx.x & 63;
  int i = blockIdx.x*4 + w;
  int c = lane*2;
  if (i < NT1){
    int b = i / LQ; int r = i % LQ;
    int t = r / (P_*L_); int rp = r % (P_*L_);
    int p = rp / L_; int lv = rp % L_;
    const float* xrow = x + (((size_t)(b*T_+t)*P_ + p)*LL + 1 + lv)*C_;
    float2 v = *(const float2*)(xrow + c);
    float s1 = v.x + v.y, s2 = v.x*v.x + v.y*v.y;
    #pragma unroll
    for (int d=1; d<64; d<<=1){ s1 += __shfl_xor(s1,d); s2 += __shfl_xor(s2,d); }
    float mean = s1*(1.0f/C_);
    float var  = s2*(1.0f/C_) - mean*mean;
    float inv = rsqrtf(var + 1e-5f);
    float2 gg = *(const float2*)(g1 + c);
    float2 bb = *(const float2*)(be1 + c);
    float xn0 = (v.x - mean)*inv*gg.x + bb.x;
    float xn1 = (v.y - mean)*inv*gg.y + bb.y;
    size_t oi = (size_t)i*C_ + c;
    *(unsigned*)(xn + oi) = (unsigned)f2bf(xn0) | ((unsigned)f2bf(xn1) << 16);
    size_t pidx = (((size_t)t*P_ + p)*L_ + lv)*C_ + c;
    float2 pv = *(const float2*)(pe + pidx);
    float2 lp = *(const float2*)(lpos + pidx);
    *(unsigned*)(q + oi) = (unsigned)f2bf(xn0 + pv.x + lp.x) | ((unsigned)f2bf(xn1 + pv.y + lp.y) << 16);
  } else {
    int i0 = i - NT1;                  // btp index
    if (i0 >= B_*T_*P_) return;
    size_t xrow = (size_t)i0*LL;       // lv0 row in xcat/xn2
    const float* xr = x + xrow*C_;
    float2 v = *(const float2*)(xr + c);
    float s1 = v.x + v.y, s2 = v.x*v.x + v.y*v.y;
    #pragma unroll
    for (int d=1; d<64; d<<=1){ s1 += __shfl_xor(s1,d); s2 += __shfl_xor(s2,d); }
    float mean = s1*(1.0f/C_);
    float var  = s2*(1.0f/C_) - mean*mean;
    float inv = rsqrtf(var + 1e-5f);
    float2 gg = *(const float2*)(g2 + c);
    float2 bb = *(const float2*)(be2 + c);
    *(float2*)(xcat + xrow*C_ + c) = v;
    float o0 = (v.x - mean)*inv*gg.x + bb.x;
    float o1 = (v.y - mean)*inv*gg.y + bb.y;
    *(unsigned*)(xn2 + xrow*C_ + c) = (unsigned)f2bf(o0) | ((unsigned)f2bf(o1) << 16);
  }
}

// ---------------- tiled bf16 MFMA GEMM v2 ----------------
// BM=64, BN=128. Row-major LDS tiles with XOR chunk swizzle (pos = chunk ^ (row&7));
// staged via global_load_lds: linear LDS dest + pre-swizzled per-lane SOURCE chunk.
// EPI: 3 fp32 +res   4 GELU->bf16   5 plain bf16
//      6 OUT1: scatter xcat=v+xres(x), LN(row)->outB(xn2)   [N==128]
//      7 OUT2: xcat=v+res (in place), LN(row)->outB(ln3)    [N==128]
template<int K, int N, int EPI>
__global__ __launch_bounds__(256) void k_mm(
    const unsigned short* __restrict__ A, const unsigned short* __restrict__ Bw,
    const float* __restrict__ bias, const float* __restrict__ res,
    float* __restrict__ outF, unsigned short* __restrict__ outB,
    const float* __restrict__ xres, const float* __restrict__ lng,
    const float* __restrict__ lnbe, int M)
{
  constexpr int NST = K / 128;
  __shared__ unsigned short As[64*128];
  __shared__ unsigned short Bs[128*128];
  int tid = threadIdx.x;
  int lane = tid & 63;
  int w = tid >> 6;
  int lr = lane & 15, kg = lane >> 4;
  int m0 = blockIdx.x * 64;
  int n0 = blockIdx.y * 128;
  int lrow = lane >> 4;
  int lch  = lane & 15;
  float4v acc[8] = {};
  for (int st = 0; st < NST; ++st){
    int kk = st*128;
    if (st) __syncthreads();
    #pragma unroll
    for (int j = 0; j < 4; ++j){
      int rb = w*16 + j*4;
      int srcch = lch ^ ((rb + lrow) & 7);
      dma16(A + (size_t)(m0 + rb + lrow)*K + kk + srcch*8, As + rb*128);
    }
    #pragma unroll
    for (int j = 0; j < 8; ++j){
      int rb = w*32 + j*4;
      int srcch = lch ^ ((rb + lrow) & 7);
      dma16(Bw + (size_t)(n0 + rb + lrow)*K + kk + srcch*8, Bs + rb*128);
    }
    __syncthreads();
    #pragma unroll
    for (int ks = 0; ks < 4; ++ks){
      int cn = ks*4 + kg;
      int arow = w*16 + lr;
      short8v af = *(const short8v*)(As + arow*128 + ((cn ^ (arow & 7)) * 8));
      #pragma unroll
      for (int nf = 0; nf < 8; ++nf){
        int brow = nf*16 + lr;
        short8v bf = *(const short8v*)(Bs + brow*128 + ((cn ^ (brow & 7)) * 8));
        acc[nf] = __builtin_amdgcn_mfma_f32_16x16x32_bf16(af, bf, acc[nf], 0, 0, 0);
      }
    }
  }
  // D row = m0 + w*16 + kg*4 + j, col = n0 + nf*16 + lr  (gr uniform across the lr group)
  #pragma unroll
  for (int j = 0; j < 4; ++j){
    int gr = m0 + w*16 + kg*4 + j;
    if (gr >= M) continue;
    if (EPI == 3 || EPI == 4 || EPI == 5){
      #pragma unroll
      for (int nf = 0; nf < 8; ++nf){
        int gc = n0 + nf*16 + lr;
        float v = acc[nf][j] + bias[gc];
        if (EPI == 3) {
          outF[(size_t)gr*N + gc] = v + res[(size_t)gr*N + gc];
        } else if (EPI == 4) {
          float gv = 0.5f*v*(1.0f + erff(v*0.70710678118654752440f));
          outB[(size_t)gr*N + gc] = f2bf(gv);
        } else {
          outB[(size_t)gr*N + gc] = f2bf(v);
        }
      }
    } else {
      size_t xrow;
      if (EPI == 6){
        int b = gr / LQ; int r = gr % LQ;
        int t = r / (P_*L_); int rp = r % (P_*L_);
        int p = rp / L_; int lv = rp % L_;
        xrow = (((size_t)(b*T_+t)*P_ + p)*LL) + 1 + lv;
      } else {
        xrow = (size_t)gr;
      }
      float vals[8];
      float s = 0.f, sq = 0.f;
      #pragma unroll
      for (int nf = 0; nf < 8; ++nf){
        int gc = n0 + nf*16 + lr;
        float v = acc[nf][j] + bias[gc];
        if (EPI == 6) v += xres[xrow*C_ + gc];
        else          v += res[xrow*C_ + gc];
        vals[nf] = v; s += v; sq += v*v;
      }
      #pragma unroll
      for (int d = 1; d < 16; d <<= 1){ s += __shfl_xor(s, d); sq += __shfl_xor(sq, d); }
      float mean = s*(1.0f/128.f);
      float varr = sq*(1.0f/128.f) - mean*mean;
      float linv = rsqrtf(varr + 1e-5f);
      #pragma unroll
      for (int nf = 0; nf < 8; ++nf){
        int gc = n0 + nf*16 + lr;
        outF[xrow*C_ + gc] = vals[nf];
        float ln = (vals[nf] - mean)*linv*lng[gc] + lnbe[gc];
        outB[xrow*C_ + gc] = f2bf(ln);
      }
    }
  }
}

// ---------------- merged Q-branch GEMM: off(y=0,1) / attn-logits(y=2) / val(y=3) ----------------
__global__ __launch_bounds__(256) void k_mm3(
    const unsigned short* __restrict__ Aq, const unsigned short* __restrict__ Axn,
    const unsigned short* __restrict__ Bw,           // 512 rows x 128
    const float* __restrict__ b_off, const float* __restrict__ b_attn,
    const float* __restrict__ b_val,
    unsigned short* __restrict__ off_b, unsigned short* __restrict__ aw_b,
    unsigned short* __restrict__ vm_b, int M)
{
  __shared__ unsigned short As[64*128];
  __shared__ unsigned short Bs[128*128];
  int tid = threadIdx.x;
  int lane = tid & 63;
  int w = tid >> 6;
  int lr = lane & 15, kg = lane >> 4;
  int m0 = blockIdx.x * 64;
  int y  = blockIdx.y;
  int n0 = y * 128;
  const unsigned short* A = (y == 3) ? Axn : Aq;
  int lrow = lane >> 4;
  int lch  = lane & 15;
  float4v acc[8] = {};
  #pragma unroll
  for (int j = 0; j < 4; ++j){
    int rb = w*16 + j*4;
    int srcch = lch ^ ((rb + lrow) & 7);
    dma16(A + (size_t)(m0 + rb + lrow)*128 + srcch*8, As + rb*128);
  }
  #pragma unroll
  for (int j = 0; j < 8; ++j){
    int rb = w*32 + j*4;
    int srcch = lch ^ ((rb + lrow) & 7);
    dma16(Bw + (size_t)(n0 + rb + lrow)*128 + srcch*8, Bs + rb*128);
  }
  __syncthreads();
  #pragma unroll
  for (int ks = 0; ks < 4; ++ks){
    int cn = ks*4 + kg;
    int arow = w*16 + lr;
    short8v af = *(const short8v*)(As + arow*128 + ((cn ^ (arow & 7)) * 8));
    #pragma unroll
    for (int nf = 0; nf < 8; ++nf){
      int brow = nf*16 + lr;
      short8v bf = *(const short8v*)(Bs + brow*128 + ((cn ^ (brow & 7)) * 8));
      acc[nf] = __builtin_amdgcn_mfma_f32_16x16x32_bf16(af, bf, acc[nf], 0, 0, 0);
    }
  }
  const float* bias = (y < 2) ? b_off : (y == 2 ? b_attn - 256 : b_val - 384);
  #pragma unroll
  for (int j = 0; j < 4; ++j){
    int gr = m0 + w*16 + kg*4 + j;
    if (gr >= M) continue;
    #pragma unroll
    for (int nf = 0; nf < 8; ++nf){
      int gc = n0 + nf*16 + lr;
      float v = acc[nf][j] + bias[gc];
      unsigned short bv = f2bf(v);
      if (y < 2)      off_b[(size_t)gr*256 + gc]       = bv;
      else if (y==2)  aw_b [(size_t)gr*128 + gc - 256] = bv;
      else            vm_b [(size_t)gr*128 + gc - 384] = bv;
    }
  }
}

// ---------------- fused softmax + deformable sampling (v1 body + XCD swizzle) ----------------
#define SMP1_B ((NT1*H_ + 255)/256)   /* 1033 blocks */
__global__ __launch_bounds__(256) void k_sample(
    const unsigned short* __restrict__ off, const unsigned short* __restrict__ awl,
    const float* __restrict__ refp, const unsigned short* __restrict__ vmap,
    unsigned short* __restrict__ o){
  // bijective XCD swizzle (m204): consecutive logical blocks (= consecutive tokens,
  // overlapping vmap rows) land on the same XCD's L2.
  const int nB = SMP1_B, q8 = nB >> 3, r8 = nB & 7;
  int xcd = blockIdx.x & 7, idx8 = blockIdx.x >> 3;
  int lb = (xcd < r8) ? xcd*(q8+1) + idx8 : r8*(q8+1) + (xcd - r8)*q8 + idx8;
  int gid = lb*256 + threadIdx.x;
  if (gid >= NT1*H_) return;
  int h = gid & 7; int i = gid >> 3;
  int b = i / LQ; int r = i % LQ;
  int t = r/(P_*L_); int rp = r%(P_*L_); int p = rp/L_;
  size_t rpi = (((size_t)b*T_+t)*P_+p)*2;
  float refx = refp[rpi + 0]*P_ - 0.5f;
  float refy = refp[rpi + 1]*T_ - 0.5f;

  float offv[32];
  {
    const short8v* op8 = (const short8v*)(off + (size_t)i*256 + h*32);
    #pragma unroll
    for (int s=0;s<4;++s){ short8v v = op8[s];
      #pragma unroll
      for (int j=0;j<8;++j) offv[s*8+j] = bf2f((unsigned short)v[j]); }
  }
  float awv[16];
  {
    const short8v* ap8 = (const short8v*)(awl + (size_t)i*128 + h*16);
    #pragma unroll
    for (int s=0;s<2;++s){ short8v v = ap8[s];
      #pragma unroll
      for (int j=0;j<8;++j) awv[s*8+j] = bf2f((unsigned short)v[j]); }
  }
  float m = awv[0];
  #pragma unroll
  for (int k=1;k<16;++k) m = fmaxf(m, awv[k]);
  float sum = 0.f;
  #pragma unroll
  for (int k=0;k<16;++k){ awv[k] = __expf(awv[k]-m); sum += awv[k]; }
  float inv = 1.f/sum;
  #pragma unroll
  for (int k=0;k<16;++k) awv[k] *= inv;

  float acc[16];
  #pragma unroll
  for (int d=0;d<16;++d) acc[d]=0.f;

  #pragma unroll
  for (int lv=0; lv<L_; ++lv){
    const unsigned short* vlv = vmap + ((size_t)b*LQ + lv)*128 + h*16;
    #pragma unroll
    for (int pt=0; pt<NPTS_; ++pt){
      float px = refx + offv[(lv*4+pt)*2+0];
      float py = refy + offv[(lv*4+pt)*2+1];
      float w  = awv[lv*4+pt];
      float fx = floorf(px), fy = floorf(py);
      int x0 = (int)fx, y0 = (int)fy;
      float wx1 = px - fx, wx0 = 1.f - wx1;
      float wy1 = py - fy, wy0 = 1.f - wy1;
      float cw[4] = {w*wy0*wx0, w*wy0*wx1, w*wy1*wx0, w*wy1*wx1};
      int ys[4] = {y0, y0, y0+1, y0+1};
      int xs[4] = {x0, x0+1, x0, x0+1};
      #pragma unroll
      for (int cidx=0; cidx<4; ++cidx){
        int yy = ys[cidx], xx = xs[cidx];
        if (yy>=0 && yy<T_ && xx>=0 && xx<P_){
          const short8v* vp = (const short8v*)(vlv + (size_t)(yy*P_ + xx)*(L_*128));
          short8v v0 = vp[0], v1 = vp[1];
          float wgt = cw[cidx];
          #pragma unroll
          for (int d=0;d<8;++d){
            acc[d]   = fmaf(wgt, bf2f((unsigned short)v0[d]), acc[d]);
            acc[8+d] = fmaf(wgt, bf2f((unsigned short)v1[d]), acc[8+d]);
          }
        }
      }
    }
  }
  short8v o0, o1;
  #pragma unroll
  for (int d=0;d<8;++d){ o0[d] = (short)f2bf(acc[d]); o1[d] = (short)f2bf(acc[8+d]); }
  short8v* op = (short8v*)(o + (size_t)i*C_ + h*DH_);
  op[0] = o0; op[1] = o1;
}

// ---------------- MFMA flash attention v8: paired q-tiles, max-free softmax,
// register-direct PV via K=16 MFMA (QK^T output layout == PV B-fragment layout) ----------------
#ifdef HAVE_M16
#define AT7_WAVE 3648
#else
#define AT7_WAVE 6976
#endif
__global__ __launch_bounds__(128) void k_attn7(const unsigned short* __restrict__ qkv,
                                               unsigned short* __restrict__ ca){
  __shared__ unsigned short alds[2*AT7_WAVE];
  int w = threadIdx.x >> 6; int lane = threadIdx.x & 63;
  int bt = blockIdx.x >> 2; int hp = blockIdx.x & 3;
  int h = hp*2 + w;
  unsigned short* Kb  = alds + w*AT7_WAVE;
  unsigned short* Vb  = Kb + 1920;   // V^T: [d][key], stride 108
#ifndef HAVE_M16
  unsigned short* Pb0 = Kb + 3648;   // fallback: P^T tiles
  unsigned short* Pb1 = Kb + 5312;
#endif
  const unsigned short* base = qkv + (size_t)bt*85*384 + h*16;
  for (int idx = lane; idx < 192; idx += 64){
    int s = idx >> 1; int d0 = (idx & 1)*8;
    short8v kv = {}, vv = {};
    if (s < 85){
      const unsigned short* rp = base + (size_t)s*384 + d0;
      kv = *(const short8v*)(rp + 128);
      vv = *(const short8v*)(rp + 256);
    }
    *(short8v*)(Kb + s*20 + d0) = kv;
    #pragma unroll
    for (int j=0;j<8;++j) Vb[(d0+j)*108 + s] = (unsigned short)vv[j];
  }
  __syncthreads();
  int g = lane >> 4; int li = lane & 15;
  const short8v zero8 = {};
  short8v qf0 = zero8, qf1 = zero8;
  if (g < 2){
    if (li < 85) qf0 = *(const short8v*)(base + (size_t)li*384 + g*8);
    int q1i = 16 + li;
    if (q1i < 85) qf1 = *(const short8v*)(base + (size_t)q1i*384 + g*8);
  }
  #pragma unroll 1
  for (int qp = 0; qp < 3; ++qp){
    short8v qn0 = zero8, qn1 = zero8;
    if (qp < 2 && g < 2){
      int a = (qp+1)*32 + li, b2 = a + 16;
      if (a  < 85) qn0 = *(const short8v*)(base + (size_t)a *384 + g*8);
      if (b2 < 85) qn1 = *(const short8v*)(base + (size_t)b2*384 + g*8);
    }
    float4v sc0[6], sc1[6];
    __builtin_amdgcn_s_setprio(1);
    #pragma unroll
    for (int kt = 0; kt < 6; ++kt){
      short8v kf = zero8;
      if (g < 2) kf = *(const short8v*)(Kb + (kt*16 + li)*20 + g*8);
      float4v z = {};
      sc0[kt] = __builtin_amdgcn_mfma_f32_16x16x32_bf16(kf, qf0, z, 0, 0, 0);
      sc1[kt] = __builtin_amdgcn_mfma_f32_16x16x32_bf16(kf, qf1, z, 0, 0, 0);
    }
    __builtin_amdgcn_s_setprio(0);
    // max-free softmax: e = exp(s/4), masked keys -> 0
    float sum0 = 0.f, sum1 = 0.f;
    float4v o0 = {}, o1 = {};
#ifdef HAVE_M16
    // PV fused: sc regs are already the K=16 B-fragment (col=q=li, k=g*4+j)
    #pragma unroll
    for (int kt = 0; kt < 6; ++kt){
      short4v p0, p1;
      #pragma unroll
      for (int j = 0; j < 4; ++j){
        bool msk = (kt == 5 && (g*4 + j) >= 5);   // keys 85..95
        float e0 = msk ? 0.f : __expf(sc0[kt][j]*0.25f);
        float e1 = msk ? 0.f : __expf(sc1[kt][j]*0.25f);
        sum0 += e0; p0[j] = (short)f2bf(e0);
        sum1 += e1; p1[j] = (short)f2bf(e1);
      }
      short4v vf = *(const short4v*)(Vb + li*108 + kt*16 + g*4);  // A: V^T[d=li][k]
      o0 = __builtin_amdgcn_mfma_f32_16x16x16bf16_1k(vf, p0, o0, 0, 0, 0);
      o1 = __builtin_amdgcn_mfma_f32_16x16x16bf16_1k(vf, p1, o1, 0, 0, 0);
    }
#else
    #pragma unroll
    for (int kt = 0; kt < 6; ++kt){
      short4v p0, p1;
      #pragma unroll
      for (int j = 0; j < 4; ++j){
        bool msk = (kt == 5 && (g*4 + j) >= 5);
        float e0 = msk ? 0.f : __expf(sc0[kt][j]*0.25f);
        float e1 = msk ? 0.f : __expf(sc1[kt][j]*0.25f);
        sum0 += e0; p0[j] = (short)f2bf(e0);
        sum1 += e1; p1[j] = (short)f2bf(e1);
      }
      *(short4v*)(Pb0 + li*104 + kt*16 + g*4) = p0;
      *(short4v*)(Pb1 + li*104 + kt*16 + g*4) = p1;
    }
    #pragma unroll
    for (int kt32 = 0; kt32 < 3; ++kt32){
      short8v vf  = *(const short8v*)(Vb  + li*108 + kt32*32 + g*8);
      short8v p80 = *(const short8v*)(Pb0 + li*104 + kt32*32 + g*8);
      short8v p81 = *(const short8v*)(Pb1 + li*104 + kt32*32 + g*8);
      o0 = __builtin_amdgcn_mfma_f32_16x16x32_bf16(vf, p80, o0, 0, 0, 0);
      o1 = __builtin_amdgcn_mfma_f32_16x16x32_bf16(vf, p81, o1, 0, 0, 0);
    }
#endif
    sum0 += __shfl_xor(sum0, 16); sum1 += __shfl_xor(sum1, 16);
    sum0 += __shfl_xor(sum0, 32); sum1 += __shfl_xor(sum1, 32);
    float inv0 = 1.f/sum0, inv1 = 1.f/sum1;
    int q0 = qp*32 + li, q1 = q0 + 16;
    if (q0 < 85){
      short4v ov;
      #pragma unroll
      for (int j=0;j<4;++j) ov[j] = (short)f2bf(o0[j]*inv0);
      *(short4v*)(ca + ((size_t)bt*85 + q0)*128 + h*16 + g*4) = ov;
    }
    if (q1 < 85){
      short4v ov;
      #pragma unroll
      for (int j=0;j<4;++j) ov[j] = (short)f2bf(o1[j]*inv1);
      *(short4v*)(ca + ((size_t)bt*85 + q1)*128 + h*16 + g*4) = ov;
    }
    qf0 = qn0; qf1 = qn1;
  }
}

extern "C" void kernel_launch(void* const* d_in, const int* in_sizes, int n_in,
                              void* d_out, int out_size, void* d_ws, size_t ws_size,
                              hipStream_t stream) {
  (void)in_sizes; (void)n_in; (void)out_size; (void)ws_size;
  const float* x      = (const float*)d_in[0];
  const float* refp   = (const float*)d_in[1];
  const float* pe     = (const float*)d_in[2];
  const float* lpos   = (const float*)d_in[3];
  const float* w_off  = (const float*)d_in[4];
  const float* b_off  = (const float*)d_in[5];
  const float* w_attn = (const float*)d_in[6];
  const float* b_attn = (const float*)d_in[7];
  const float* w_val  = (const float*)d_in[8];
  const float* b_val  = (const float*)d_in[9];
  const float* w_out  = (const float*)d_in[10];
  const float* b_out  = (const float*)d_in[11];
  const float* in_w   = (const float*)d_in[12];
  const float* in_b   = (const float*)d_in[13];
  const float* out_w  = (const float*)d_in[14];
  const float* out_b  = (const float*)d_in[15];
  const float* fc1_w  = (const float*)d_in[16];
  const float* fc1_b  = (const float*)d_in[17];
  const float* fc2_w  = (const float*)d_in[18];
  const float* fc2_b  = (const float*)d_in[19];
  const float* g1     = (const float*)d_in[20];
  const float* be1    = (const float*)d_in[21];
  const float* g2     = (const float*)d_in[22];
  const float* be2    = (const float*)d_in[23];
  const float* g3     = (const float*)d_in[24];
  const float* be3    = (const float*)d_in[25];
  float* out = (float*)d_out;
  char* wsb = (char*)d_ws;

  // ---- workspace layout (byte offsets) ----
  unsigned short* xn_b  = (unsigned short*)(wsb + 0);            // NT1*128 bf16
  unsigned short* q_b   = (unsigned short*)(wsb + 8460288);      // NT1*128 bf16
  unsigned short* off_b = (unsigned short*)(wsb + 16920576);     // NT1*256 bf16
  unsigned short* aw_b  = (unsigned short*)(wsb + 33841152);     // NT1*128 bf16
  unsigned short* vm_b  = (unsigned short*)(wsb + 42301440);     // NT1*128 bf16
  unsigned short* o_b   = (unsigned short*)(wsb + 50761728);     // NT1*128 bf16
  float*          xcatB = (float*)(wsb + 59222016);              // NT2*128 f32
  unsigned short* xn2_b = (unsigned short*)(wsb + 80372736);     // NT2*128 bf16
  unsigned short* qkv_b = (unsigned short*)(wsb + 90948096);     // NT2*384 bf16
  unsigned short* wb    = (unsigned short*)(wsb + 122674176);    // 278528 bf16
  // reuse of dead regions:
  unsigned short* ca_b  = (unsigned short*)(wsb + 0);            // NT2*128 bf16 (xn+q dead)
  unsigned short* ln3_b = (unsigned short*)(wsb + 80372736);     // xn2 dead
  unsigned short* hid_b = (unsigned short*)(wsb + 16920576);     // NT2*512 bf16 (off..o dead)

  unsigned short* wb_off  = wb + 0;       // rows 0..255 off, 256..383 attn, 384..511 val
  unsigned short* wb_wout = wb + 65536;
  unsigned short* wb_in   = wb + 81920;
  unsigned short* wb_outw = wb + 131072;
  unsigned short* wb_fc1  = wb + 147456;
  unsigned short* wb_fc2  = wb + 212992;

  const int GM1 = (NT1 + 63)/64;  // 517
  const int GM2 = (NT2 + 63)/64;  // 646

  // 0. weights -> bf16
  hipLaunchKernelGGL(k_wcvt, dim3((278528+255)/256), dim3(256), 0, stream,
                     w_off, w_attn, w_val, w_out, in_w, out_w, fc1_w, fc2_w, wb);
  // 1. LN1 + q (lv1..4) + x0-row copy/LN2 (merged)
  hipLaunchKernelGGL(k_ln1_q, dim3((NT1 + B_*T_*P_ + 3)/4), dim3(256), 0, stream,
                     x, pe, lpos, g1, be1, g2, be2, xn_b, q_b, xcatB, xn2_b);
  // 2. merged off / attn-logits / val
  hipLaunchKernelGGL(k_mm3, dim3(GM1,4), dim3(256), 0, stream,
                     q_b, xn_b, wb_off, b_off, b_attn, b_val, off_b, aw_b, vm_b, NT1);
  // 3. fused softmax + deformable sampling (XCD-swizzled)
  hipLaunchKernelGGL(k_sample, dim3(SMP1_B), dim3(256), 0, stream,
                     off_b, aw_b, refp, vm_b, o_b);
  // 4. out-proj1 + residual + LN2 -> xcat fp32 + xn2 bf16 (lv1..4)
  hipLaunchKernelGGL((k_mm<128,128,6>), dim3(GM1,1), dim3(256), 0, stream,
                     o_b, wb_wout, b_out, nullptr, xcatB, xn2_b, x, g2, be2, NT1);
  // 5. qkv (bf16)
  hipLaunchKernelGGL((k_mm<128,384,5>), dim3(GM2,3), dim3(256), 0, stream,
                     xn2_b, wb_in, in_b, nullptr, nullptr, qkv_b, nullptr, nullptr, nullptr, NT2);
  // 6. MFMA flash attention v8 (register-direct PV)
  hipLaunchKernelGGL(k_attn7, dim3(B_*T_*4), dim3(128), 0, stream, qkv_b, ca_b);
  // 7. out-proj2 + residual + LN3 -> xcat fp32 (in place) + ln3 bf16
  hipLaunchKernelGGL((k_mm<128,128,7>), dim3(GM2,1), dim3(256), 0, stream,
                     ca_b, wb_outw, out_b, xcatB, xcatB, ln3_b, nullptr, g3, be3, NT2);
  // 8. FFN
  hipLaunchKernelGGL((k_mm<128,512,4>), dim3(GM2,4), dim3(256), 0, stream,
                     ln3_b, wb_fc1, fc1_b, nullptr, nullptr, hid_b, nullptr, nullptr, nullptr, NT2);
  hipLaunchKernelGGL((k_mm<512,128,3>), dim3(GM2,1), dim3(256), 0, stream,
                     hid_b, wb_fc2, fc2_b, xcatB, out, nullptr, nullptr, nullptr, nullptr, NT2);
}

// Round 18
// 198.808 us; speedup vs baseline: 1.0084x; 1.0084x over previous
//
#include <hip/hip_runtime.h>
#include <math.h>

#define T_ 243
#define P_ 17
#define L_ 4
#define C_ 128
#define H_ 8
#define NPTS_ 4
#define DH_ 16
#define B_ 2
#define LQ (T_*P_*L_)      /* 16524 */
#define NT1 (B_*LQ)        /* 33048 */
#define LL (L_+1)          /* 5 */
#define S_ (P_*LL)         /* 85 */
#define NT2 (B_*T_*P_*LL)  /* 41310 */

typedef __attribute__((ext_vector_type(8))) short short8v;
typedef __attribute__((ext_vector_type(4))) short short4v;
typedef __attribute__((ext_vector_type(4))) float float4v;

#if defined(__has_builtin)
# if __has_builtin(__builtin_amdgcn_mfma_f32_16x16x16bf16_1k)
#  define HAVE_M16 1
# endif
#endif

__device__ __forceinline__ unsigned short f2bf(float f){
  union { float f; unsigned u; } un; un.f = f;
  unsigned r = un.u + 0x7FFF + ((un.u >> 16) & 1);   // RNE
  return (unsigned short)(r >> 16);
}
__device__ __forceinline__ float bf2f(unsigned short u){
  union { unsigned u; float f; } un; un.u = ((unsigned)u) << 16; return un.f;
}
// async global->LDS DMA, 16B per lane; dest = wave-uniform base + lane*16 (linear).
__device__ __forceinline__ void dma16(const unsigned short* g, unsigned short* l){
  __builtin_amdgcn_global_load_lds(
      (const __attribute__((address_space(1))) void*)g,
      (__attribute__((address_space(3))) void*)l, 16, 0, 0);
}

// ---------------- weight convert fp32 -> bf16, layout preserved [N][K] ----------------
__global__ void k_wcvt(const float* __restrict__ w0, const float* __restrict__ w1,
                       const float* __restrict__ w2, const float* __restrict__ w3,
                       const float* __restrict__ w4, const float* __restrict__ w5,
                       const float* __restrict__ w6, const float* __restrict__ w7,
                       unsigned short* __restrict__ dst){
  int i = blockIdx.x*256 + threadIdx.x;
  if (i >= 278528) return;
  float v;
  if      (i < 32768)  v = w0[i];
  else if (i < 49152)  v = w1[i-32768];
  else if (i < 65536)  v = w2[i-49152];
  else if (i < 81920)  v = w3[i-65536];
  else if (i < 131072) v = w4[i-81920];
  else if (i < 147456) v = w5[i-131072];
  else if (i < 212992) v = w6[i-147456];
  else                 v = w7[i-212992];
  dst[i] = f2bf(v);
}

// ---------------- LN1 + q (lv1..4 rows) AND x0-row copy+LN2 (merged) ----------------
__global__ __launch_bounds__(256) void k_ln1_q(
    const float* __restrict__ x, const float* __restrict__ pe,
    const float* __restrict__ lpos, const float* __restrict__ g1,
    const float* __restrict__ be1, const float* __restrict__ g2,
    const float* __restrict__ be2, unsigned short* __restrict__ xn,
    unsigned short* __restrict__ q, float* __restrict__ xcat,
    unsigned short* __restrict__ xn2) {
  int w = threadIdx.x >> 6; int lane = threadIdx.x & 63;
  int i = blockIdx.x*4 + w;
  int c = lane*2;
  if (i < NT1){
    int b = i / LQ; int r = i % LQ;
    int t = r / (P_*L_); int rp = r % (P_*L_);
    int p = rp / L_; int lv = rp % L_;
    const float* xrow = x + (((size_t)(b*T_+t)*P_ + p)*LL + 1 + lv)*C_;
    float2 v = *(const float2*)(xrow + c);
    float s1 = v.x + v.y, s2 = v.x*v.x + v.y*v.y;
    #pragma unroll
    for (int d=1; d<64; d<<=1){ s1 += __shfl_xor(s1,d); s2 += __shfl_xor(s2,d); }
    float mean = s1*(1.0f/C_);
    float var  = s2*(1.0f/C_) - mean*mean;
    float inv = rsqrtf(var + 1e-5f);
    float2 gg = *(const float2*)(g1 + c);
    float2 bb = *(const float2*)(be1 + c);
    float xn0 = (v.x - mean)*inv*gg.x + bb.x;
    float xn1 = (v.y - mean)*inv*gg.y + bb.y;
    size_t oi = (size_t)i*C_ + c;
    *(unsigned*)(xn + oi) = (unsigned)f2bf(xn0) | ((unsigned)f2bf(xn1) << 16);
    size_t pidx = (((size_t)t*P_ + p)*L_ + lv)*C_ + c;
    float2 pv = *(const float2*)(pe + pidx);
    float2 lp = *(const float2*)(lpos + pidx);
    *(unsigned*)(q + oi) = (unsigned)f2bf(xn0 + pv.x + lp.x) | ((unsigned)f2bf(xn1 + pv.y + lp.y) << 16);
  } else {
    int i0 = i - NT1;                  // btp index
    if (i0 >= B_*T_*P_) return;
    size_t xrow = (size_t)i0*LL;       // lv0 row in xcat/xn2
    const float* xr = x + xrow*C_;
    float2 v = *(const float2*)(xr + c);
    float s1 = v.x + v.y, s2 = v.x*v.x + v.y*v.y;
    #pragma unroll
    for (int d=1; d<64; d<<=1){ s1 += __shfl_xor(s1,d); s2 += __shfl_xor(s2,d); }
    float mean = s1*(1.0f/C_);
    float var  = s2*(1.0f/C_) - mean*mean;
    float inv = rsqrtf(var + 1e-5f);
    float2 gg = *(const float2*)(g2 + c);
    float2 bb = *(const float2*)(be2 + c);
    *(float2*)(xcat + xrow*C_ + c) = v;
    float o0 = (v.x - mean)*inv*gg.x + bb.x;
    float o1 = (v.y - mean)*inv*gg.y + bb.y;
    *(unsigned*)(xn2 + xrow*C_ + c) = (unsigned)f2bf(o0) | ((unsigned)f2bf(o1) << 16);
  }
}

// ---------------- tiled bf16 MFMA GEMM v2 (single-N) ----------------
// EPI: 3 fp32 +res   6 OUT1: scatter xcat=v+xres(x), LN(row)->outB(xn2)
//      7 OUT2: xcat=v+res (in place), LN(row)->outB(ln3)
template<int K, int N, int EPI>
__global__ __launch_bounds__(256) void k_mm(
    const unsigned short* __restrict__ A, const unsigned short* __restrict__ Bw,
    const float* __restrict__ bias, const float* __restrict__ res,
    float* __restrict__ outF, unsigned short* __restrict__ outB,
    const float* __restrict__ xres, const float* __restrict__ lng,
    const float* __restrict__ lnbe, int M)
{
  constexpr int NST = K / 128;
  __shared__ unsigned short As[64*128];
  __shared__ unsigned short Bs[128*128];
  int tid = threadIdx.x;
  int lane = tid & 63;
  int w = tid >> 6;
  int lr = lane & 15, kg = lane >> 4;
  int m0 = blockIdx.x * 64;
  int n0 = blockIdx.y * 128;
  int lrow = lane >> 4;
  int lch  = lane & 15;
  float4v acc[8] = {};
  for (int st = 0; st < NST; ++st){
    int kk = st*128;
    if (st) __syncthreads();
    #pragma unroll
    for (int j = 0; j < 4; ++j){
      int rb = w*16 + j*4;
      int srcch = lch ^ ((rb + lrow) & 7);
      dma16(A + (size_t)(m0 + rb + lrow)*K + kk + srcch*8, As + rb*128);
    }
    #pragma unroll
    for (int j = 0; j < 8; ++j){
      int rb = w*32 + j*4;
      int srcch = lch ^ ((rb + lrow) & 7);
      dma16(Bw + (size_t)(n0 + rb + lrow)*K + kk + srcch*8, Bs + rb*128);
    }
    __syncthreads();
    #pragma unroll
    for (int ks = 0; ks < 4; ++ks){
      int cn = ks*4 + kg;
      int arow = w*16 + lr;
      short8v af = *(const short8v*)(As + arow*128 + ((cn ^ (arow & 7)) * 8));
      #pragma unroll
      for (int nf = 0; nf < 8; ++nf){
        int brow = nf*16 + lr;
        short8v bf = *(const short8v*)(Bs + brow*128 + ((cn ^ (brow & 7)) * 8));
        acc[nf] = __builtin_amdgcn_mfma_f32_16x16x32_bf16(af, bf, acc[nf], 0, 0, 0);
      }
    }
  }
  #pragma unroll
  for (int j = 0; j < 4; ++j){
    int gr = m0 + w*16 + kg*4 + j;
    if (gr >= M) continue;
    if (EPI == 3){
      #pragma unroll
      for (int nf = 0; nf < 8; ++nf){
        int gc = n0 + nf*16 + lr;
        float v = acc[nf][j] + bias[gc];
        outF[(size_t)gr*N + gc] = v + res[(size_t)gr*N + gc];
      }
    } else {
      size_t xrow;
      if (EPI == 6){
        int b = gr / LQ; int r = gr % LQ;
        int t = r / (P_*L_); int rp = r % (P_*L_);
        int p = rp / L_; int lv = rp % L_;
        xrow = (((size_t)(b*T_+t)*P_ + p)*LL) + 1 + lv;
      } else {
        xrow = (size_t)gr;
      }
      float vals[8];
      float s = 0.f, sq = 0.f;
      #pragma unroll
      for (int nf = 0; nf < 8; ++nf){
        int gc = n0 + nf*16 + lr;
        float v = acc[nf][j] + bias[gc];
        if (EPI == 6) v += xres[xrow*C_ + gc];
        else          v += res[xrow*C_ + gc];
        vals[nf] = v; s += v; sq += v*v;
      }
      #pragma unroll
      for (int d = 1; d < 16; d <<= 1){ s += __shfl_xor(s, d); sq += __shfl_xor(sq, d); }
      float mean = s*(1.0f/128.f);
      float varr = sq*(1.0f/128.f) - mean*mean;
      float linv = rsqrtf(varr + 1e-5f);
      #pragma unroll
      for (int nf = 0; nf < 8; ++nf){
        int gc = n0 + nf*16 + lr;
        outF[xrow*C_ + gc] = vals[nf];
        float ln = (vals[nf] - mean)*linv*lng[gc] + lnbe[gc];
        outB[xrow*C_ + gc] = f2bf(ln);
      }
    }
  }
}

// ---------------- panel-looped GEMM: K=128, N = NPANEL*128, A staged ONCE ----------------
// fc2-style serial panel loop (validated phase shape). EPI: 4 GELU->bf16, 5 plain bf16.
template<int NPANEL, int EPI>
__global__ __launch_bounds__(256) void k_mmp(
    const unsigned short* __restrict__ A, const unsigned short* __restrict__ Bw,
    const float* __restrict__ bias, unsigned short* __restrict__ outB, int M)
{
  constexpr int N = NPANEL*128;
  __shared__ unsigned short As[64*128];
  __shared__ unsigned short Bs[128*128];
  int tid = threadIdx.x;
  int lane = tid & 63;
  int w = tid >> 6;
  int lr = lane & 15, kg = lane >> 4;
  int m0 = blockIdx.x * 64;
  int lrow = lane >> 4;
  int lch  = lane & 15;
  #pragma unroll
  for (int j = 0; j < 4; ++j){
    int rb = w*16 + j*4;
    int srcch = lch ^ ((rb + lrow) & 7);
    dma16(A + (size_t)(m0 + rb + lrow)*128 + srcch*8, As + rb*128);
  }
  #pragma unroll
  for (int j = 0; j < 8; ++j){
    int rb = w*32 + j*4;
    int srcch = lch ^ ((rb + lrow) & 7);
    dma16(Bw + (size_t)(rb + lrow)*128 + srcch*8, Bs + rb*128);
  }
  __syncthreads();
  for (int pn = 0; pn < NPANEL; ++pn){
    float4v acc[8] = {};
    #pragma unroll
    for (int ks = 0; ks < 4; ++ks){
      int cn = ks*4 + kg;
      int arow = w*16 + lr;
      short8v af = *(const short8v*)(As + arow*128 + ((cn ^ (arow & 7)) * 8));
      #pragma unroll
      for (int nf = 0; nf < 8; ++nf){
        int brow = nf*16 + lr;
        short8v bf = *(const short8v*)(Bs + brow*128 + ((cn ^ (brow & 7)) * 8));
        acc[nf] = __builtin_amdgcn_mfma_f32_16x16x32_bf16(af, bf, acc[nf], 0, 0, 0);
      }
    }
    #pragma unroll
    for (int j = 0; j < 4; ++j){
      int gr = m0 + w*16 + kg*4 + j;
      if (gr >= M) continue;
      #pragma unroll
      for (int nf = 0; nf < 8; ++nf){
        int gc = nf*16 + lr;
        float v = acc[nf][j] + bias[pn*128 + gc];
        if (EPI == 4){
          float gv = 0.5f*v*(1.0f + erff(v*0.70710678118654752440f));
          outB[(size_t)gr*N + pn*128 + gc] = f2bf(gv);
        } else {
          outB[(size_t)gr*N + pn*128 + gc] = f2bf(v);
        }
      }
    }
    if (pn + 1 < NPANEL){
      __syncthreads();                 // all Bs reads done before overwrite
      #pragma unroll
      for (int j = 0; j < 8; ++j){
        int rb = w*32 + j*4;
        int srcch = lch ^ ((rb + lrow) & 7);
        dma16(Bw + (size_t)((pn+1)*128 + rb + lrow)*128 + srcch*8, Bs + rb*128);
      }
      __syncthreads();
    }
  }
}

// ---------------- merged Q-branch GEMM: off(y=0,1) / attn-logits(y=2) / val(y=3) ----------------
__global__ __launch_bounds__(256) void k_mm3(
    const unsigned short* __restrict__ Aq, const unsigned short* __restrict__ Axn,
    const unsigned short* __restrict__ Bw,           // 512 rows x 128
    const float* __restrict__ b_off, const float* __restrict__ b_attn,
    const float* __restrict__ b_val,
    unsigned short* __restrict__ off_b, unsigned short* __restrict__ aw_b,
    unsigned short* __restrict__ vm_b, int M)
{
  __shared__ unsigned short As[64*128];
  __shared__ unsigned short Bs[128*128];
  int tid = threadIdx.x;
  int lane = tid & 63;
  int w = tid >> 6;
  int lr = lane & 15, kg = lane >> 4;
  int m0 = blockIdx.x * 64;
  int y  = blockIdx.y;
  int n0 = y * 128;
  const unsigned short* A = (y == 3) ? Axn : Aq;
  int lrow = lane >> 4;
  int lch  = lane & 15;
  float4v acc[8] = {};
  #pragma unroll
  for (int j = 0; j < 4; ++j){
    int rb = w*16 + j*4;
    int srcch = lch ^ ((rb + lrow) & 7);
    dma16(A + (size_t)(m0 + rb + lrow)*128 + srcch*8, As + rb*128);
  }
  #pragma unroll
  for (int j = 0; j < 8; ++j){
    int rb = w*32 + j*4;
    int srcch = lch ^ ((rb + lrow) & 7);
    dma16(Bw + (size_t)(n0 + rb + lrow)*128 + srcch*8, Bs + rb*128);
  }
  __syncthreads();
  #pragma unroll
  for (int ks = 0; ks < 4; ++ks){
    int cn = ks*4 + kg;
    int arow = w*16 + lr;
    short8v af = *(const short8v*)(As + arow*128 + ((cn ^ (arow & 7)) * 8));
    #pragma unroll
    for (int nf = 0; nf < 8; ++nf){
      int brow = nf*16 + lr;
      short8v bf = *(const short8v*)(Bs + brow*128 + ((cn ^ (brow & 7)) * 8));
      acc[nf] = __builtin_amdgcn_mfma_f32_16x16x32_bf16(af, bf, acc[nf], 0, 0, 0);
    }
  }
  const float* bias = (y < 2) ? b_off : (y == 2 ? b_attn - 256 : b_val - 384);
  #pragma unroll
  for (int j = 0; j < 4; ++j){
    int gr = m0 + w*16 + kg*4 + j;
    if (gr >= M) continue;
    #pragma unroll
    for (int nf = 0; nf < 8; ++nf){
      int gc = n0 + nf*16 + lr;
      float v = acc[nf][j] + bias[gc];
      unsigned short bv = f2bf(v);
      if (y < 2)      off_b[(size_t)gr*256 + gc]       = bv;
      else if (y==2)  aw_b [(size_t)gr*128 + gc - 256] = bv;
      else            vm_b [(size_t)gr*128 + gc - 384] = bv;
    }
  }
}

// ---------------- fused softmax + deformable sampling (v1) ----------------
__global__ __launch_bounds__(256) void k_sample(
    const unsigned short* __restrict__ off, const unsigned short* __restrict__ awl,
    const float* __restrict__ refp, const unsigned short* __restrict__ vmap,
    unsigned short* __restrict__ o){
  int gid = blockIdx.x*256 + threadIdx.x;
  if (gid >= NT1*H_) return;
  int h = gid & 7; int i = gid >> 3;
  int b = i / LQ; int r = i % LQ;
  int t = r/(P_*L_); int rp = r%(P_*L_); int p = rp/L_;
  size_t rpi = (((size_t)b*T_+t)*P_+p)*2;
  float refx = refp[rpi + 0]*P_ - 0.5f;
  float refy = refp[rpi + 1]*T_ - 0.5f;

  float offv[32];
  {
    const short8v* op8 = (const short8v*)(off + (size_t)i*256 + h*32);
    #pragma unroll
    for (int s=0;s<4;++s){ short8v v = op8[s];
      #pragma unroll
      for (int j=0;j<8;++j) offv[s*8+j] = bf2f((unsigned short)v[j]); }
  }
  float awv[16];
  {
    const short8v* ap8 = (const short8v*)(awl + (size_t)i*128 + h*16);
    #pragma unroll
    for (int s=0;s<2;++s){ short8v v = ap8[s];
      #pragma unroll
      for (int j=0;j<8;++j) awv[s*8+j] = bf2f((unsigned short)v[j]); }
  }
  float m = awv[0];
  #pragma unroll
  for (int k=1;k<16;++k) m = fmaxf(m, awv[k]);
  float sum = 0.f;
  #pragma unroll
  for (int k=0;k<16;++k){ awv[k] = __expf(awv[k]-m); sum += awv[k]; }
  float inv = 1.f/sum;
  #pragma unroll
  for (int k=0;k<16;++k) awv[k] *= inv;

  float acc[16];
  #pragma unroll
  for (int d=0;d<16;++d) acc[d]=0.f;

  #pragma unroll
  for (int lv=0; lv<L_; ++lv){
    const unsigned short* vlv = vmap + ((size_t)b*LQ + lv)*128 + h*16;
    #pragma unroll
    for (int pt=0; pt<NPTS_; ++pt){
      float px = refx + offv[(lv*4+pt)*2+0];
      float py = refy + offv[(lv*4+pt)*2+1];
      float w  = awv[lv*4+pt];
      float fx = floorf(px), fy = floorf(py);
      int x0 = (int)fx, y0 = (int)fy;
      float wx1 = px - fx, wx0 = 1.f - wx1;
      float wy1 = py - fy, wy0 = 1.f - wy1;
      float cw[4] = {w*wy0*wx0, w*wy0*wx1, w*wy1*wx0, w*wy1*wx1};
      int ys[4] = {y0, y0, y0+1, y0+1};
      int xs[4] = {x0, x0+1, x0, x0+1};
      #pragma unroll
      for (int cidx=0; cidx<4; ++cidx){
        int yy = ys[cidx], xx = xs[cidx];
        if (yy>=0 && yy<T_ && xx>=0 && xx<P_){
          const short8v* vp = (const short8v*)(vlv + (size_t)(yy*P_ + xx)*(L_*128));
          short8v v0 = vp[0], v1 = vp[1];
          float wgt = cw[cidx];
          #pragma unroll
          for (int d=0;d<8;++d){
            acc[d]   = fmaf(wgt, bf2f((unsigned short)v0[d]), acc[d]);
            acc[8+d] = fmaf(wgt, bf2f((unsigned short)v1[d]), acc[8+d]);
          }
        }
      }
    }
  }
  short8v o0, o1;
  #pragma unroll
  for (int d=0;d<8;++d){ o0[d] = (short)f2bf(acc[d]); o1[d] = (short)f2bf(acc[8+d]); }
  short8v* op = (short8v*)(o + (size_t)i*C_ + h*DH_);
  op[0] = o0; op[1] = o1;
}

// ---------------- MFMA flash attention v8: paired q-tiles, max-free softmax,
// register-direct PV via K=16 MFMA (QK^T output layout == PV B-fragment layout) ----------------
#ifdef HAVE_M16
#define AT7_WAVE 3648
#else
#define AT7_WAVE 6976
#endif
__global__ __launch_bounds__(128) void k_attn7(const unsigned short* __restrict__ qkv,
                                               unsigned short* __restrict__ ca){
  __shared__ unsigned short alds[2*AT7_WAVE];
  int w = threadIdx.x >> 6; int lane = threadIdx.x & 63;
  int bt = blockIdx.x >> 2; int hp = blockIdx.x & 3;
  int h = hp*2 + w;
  unsigned short* Kb  = alds + w*AT7_WAVE;
  unsigned short* Vb  = Kb + 1920;   // V^T: [d][key], stride 108
#ifndef HAVE_M16
  unsigned short* Pb0 = Kb + 3648;
  unsigned short* Pb1 = Kb + 5312;
#endif
  const unsigned short* base = qkv + (size_t)bt*85*384 + h*16;
  for (int idx = lane; idx < 192; idx += 64){
    int s = idx >> 1; int d0 = (idx & 1)*8;
    short8v kv = {}, vv = {};
    if (s < 85){
      const unsigned short* rp = base + (size_t)s*384 + d0;
      kv = *(const short8v*)(rp + 128);
      vv = *(const short8v*)(rp + 256);
    }
    *(short8v*)(Kb + s*20 + d0) = kv;
    #pragma unroll
    for (int j=0;j<8;++j) Vb[(d0+j)*108 + s] = (unsigned short)vv[j];
  }
  __syncthreads();
  int g = lane >> 4; int li = lane & 15;
  const short8v zero8 = {};
  short8v qf0 = zero8, qf1 = zero8;
  if (g < 2){
    if (li < 85) qf0 = *(const short8v*)(base + (size_t)li*384 + g*8);
    int q1i = 16 + li;
    if (q1i < 85) qf1 = *(const short8v*)(base + (size_t)q1i*384 + g*8);
  }
  #pragma unroll 1
  for (int qp = 0; qp < 3; ++qp){
    short8v qn0 = zero8, qn1 = zero8;
    if (qp < 2 && g < 2){
      int a = (qp+1)*32 + li, b2 = a + 16;
      if (a  < 85) qn0 = *(const short8v*)(base + (size_t)a *384 + g*8);
      if (b2 < 85) qn1 = *(const short8v*)(base + (size_t)b2*384 + g*8);
    }
    float4v sc0[6], sc1[6];
    __builtin_amdgcn_s_setprio(1);
    #pragma unroll
    for (int kt = 0; kt < 6; ++kt){
      short8v kf = zero8;
      if (g < 2) kf = *(const short8v*)(Kb + (kt*16 + li)*20 + g*8);
      float4v z = {};
      sc0[kt] = __builtin_amdgcn_mfma_f32_16x16x32_bf16(kf, qf0, z, 0, 0, 0);
      sc1[kt] = __builtin_amdgcn_mfma_f32_16x16x32_bf16(kf, qf1, z, 0, 0, 0);
    }
    __builtin_amdgcn_s_setprio(0);
    float sum0 = 0.f, sum1 = 0.f;
    float4v o0 = {}, o1 = {};
#ifdef HAVE_M16
    #pragma unroll
    for (int kt = 0; kt < 6; ++kt){
      short4v p0, p1;
      #pragma unroll
      for (int j = 0; j < 4; ++j){
        bool msk = (kt == 5 && (g*4 + j) >= 5);   // keys 85..95
        float e0 = msk ? 0.f : __expf(sc0[kt][j]*0.25f);
        float e1 = msk ? 0.f : __expf(sc1[kt][j]*0.25f);
        sum0 += e0; p0[j] = (short)f2bf(e0);
        sum1 += e1; p1[j] = (short)f2bf(e1);
      }
      short4v vf = *(const short4v*)(Vb + li*108 + kt*16 + g*4);  // A: V^T[d=li][k]
      o0 = __builtin_amdgcn_mfma_f32_16x16x16bf16_1k(vf, p0, o0, 0, 0, 0);
      o1 = __builtin_amdgcn_mfma_f32_16x16x16bf16_1k(vf, p1, o1, 0, 0, 0);
    }
#else
    #pragma unroll
    for (int kt = 0; kt < 6; ++kt){
      short4v p0, p1;
      #pragma unroll
      for (int j = 0; j < 4; ++j){
        bool msk = (kt == 5 && (g*4 + j) >= 5);
        float e0 = msk ? 0.f : __expf(sc0[kt][j]*0.25f);
        float e1 = msk ? 0.f : __expf(sc1[kt][j]*0.25f);
        sum0 += e0; p0[j] = (short)f2bf(e0);
        sum1 += e1; p1[j] = (short)f2bf(e1);
      }
      *(short4v*)(Pb0 + li*104 + kt*16 + g*4) = p0;
      *(short4v*)(Pb1 + li*104 + kt*16 + g*4) = p1;
    }
    #pragma unroll
    for (int kt32 = 0; kt32 < 3; ++kt32){
      short8v vf  = *(const short8v*)(Vb  + li*108 + kt32*32 + g*8);
      short8v p80 = *(const short8v*)(Pb0 + li*104 + kt32*32 + g*8);
      short8v p81 = *(const short8v*)(Pb1 + li*104 + kt32*32 + g*8);
      o0 = __builtin_amdgcn_mfma_f32_16x16x32_bf16(vf, p80, o0, 0, 0, 0);
      o1 = __builtin_amdgcn_mfma_f32_16x16x32_bf16(vf, p81, o1, 0, 0, 0);
    }
#endif
    sum0 += __shfl_xor(sum0, 16); sum1 += __shfl_xor(sum1, 16);
    sum0 += __shfl_xor(sum0, 32); sum1 += __shfl_xor(sum1, 32);
    float inv0 = 1.f/sum0, inv1 = 1.f/sum1;
    int q0 = qp*32 + li, q1 = q0 + 16;
    if (q0 < 85){
      short4v ov;
      #pragma unroll
      for (int j=0;j<4;++j) ov[j] = (short)f2bf(o0[j]*inv0);
      *(short4v*)(ca + ((size_t)bt*85 + q0)*128 + h*16 + g*4) = ov;
    }
    if (q1 < 85){
      short4v ov;
      #pragma unroll
      for (int j=0;j<4;++j) ov[j] = (short)f2bf(o1[j]*inv1);
      *(short4v*)(ca + ((size_t)bt*85 + q1)*128 + h*16 + g*4) = ov;
    }
    qf0 = qn0; qf1 = qn1;
  }
}

extern "C" void kernel_launch(void* const* d_in, const int* in_sizes, int n_in,
                              void* d_out, int out_size, void* d_ws, size_t ws_size,
                              hipStream_t stream) {
  (void)in_sizes; (void)n_in; (void)out_size; (void)ws_size;
  const float* x      = (const float*)d_in[0];
  const float* refp   = (const float*)d_in[1];
  const float* pe     = (const float*)d_in[2];
  const float* lpos   = (const float*)d_in[3];
  const float* w_off  = (const float*)d_in[4];
  const float* b_off  = (const float*)d_in[5];
  const float* w_attn = (const float*)d_in[6];
  const float* b_attn = (const float*)d_in[7];
  const float* w_val  = (const float*)d_in[8];
  const float* b_val  = (const float*)d_in[9];
  const float* w_out  = (const float*)d_in[10];
  const float* b_out  = (const float*)d_in[11];
  const float* in_w   = (const float*)d_in[12];
  const float* in_b   = (const float*)d_in[13];
  const float* out_w  = (const float*)d_in[14];
  const float* out_b  = (const float*)d_in[15];
  const float* fc1_w  = (const float*)d_in[16];
  const float* fc1_b  = (const float*)d_in[17];
  const float* fc2_w  = (const float*)d_in[18];
  const float* fc2_b  = (const float*)d_in[19];
  const float* g1     = (const float*)d_in[20];
  const float* be1    = (const float*)d_in[21];
  const float* g2     = (const float*)d_in[22];
  const float* be2    = (const float*)d_in[23];
  const float* g3     = (const float*)d_in[24];
  const float* be3    = (const float*)d_in[25];
  float* out = (float*)d_out;
  char* wsb = (char*)d_ws;

  // ---- workspace layout (byte offsets) ----
  unsigned short* xn_b  = (unsigned short*)(wsb + 0);            // NT1*128 bf16
  unsigned short* q_b   = (unsigned short*)(wsb + 8460288);      // NT1*128 bf16
  unsigned short* off_b = (unsigned short*)(wsb + 16920576);     // NT1*256 bf16
  unsigned short* aw_b  = (unsigned short*)(wsb + 33841152);     // NT1*128 bf16
  unsigned short* vm_b  = (unsigned short*)(wsb + 42301440);     // NT1*128 bf16
  unsigned short* o_b   = (unsigned short*)(wsb + 50761728);     // NT1*128 bf16
  float*          xcatB = (float*)(wsb + 59222016);              // NT2*128 f32
  unsigned short* xn2_b = (unsigned short*)(wsb + 80372736);     // NT2*128 bf16
  unsigned short* qkv_b = (unsigned short*)(wsb + 90948096);     // NT2*384 bf16
  unsigned short* wb    = (unsigned short*)(wsb + 122674176);    // 278528 bf16
  // reuse of dead regions:
  unsigned short* ca_b  = (unsigned short*)(wsb + 0);            // NT2*128 bf16 (xn+q dead)
  unsigned short* ln3_b = (unsigned short*)(wsb + 80372736);     // xn2 dead
  unsigned short* hid_b = (unsigned short*)(wsb + 16920576);     // NT2*512 bf16 (off..o dead)

  unsigned short* wb_off  = wb + 0;       // rows 0..255 off, 256..383 attn, 384..511 val
  unsigned short* wb_wout = wb + 65536;
  unsigned short* wb_in   = wb + 81920;
  unsigned short* wb_outw = wb + 131072;
  unsigned short* wb_fc1  = wb + 147456;
  unsigned short* wb_fc2  = wb + 212992;

  const int GM1 = (NT1 + 63)/64;  // 517
  const int GM2 = (NT2 + 63)/64;  // 646

  // 0. weights -> bf16
  hipLaunchKernelGGL(k_wcvt, dim3((278528+255)/256), dim3(256), 0, stream,
                     w_off, w_attn, w_val, w_out, in_w, out_w, fc1_w, fc2_w, wb);
  // 1. LN1 + q (lv1..4) + x0-row copy/LN2 (merged)
  hipLaunchKernelGGL(k_ln1_q, dim3((NT1 + B_*T_*P_ + 3)/4), dim3(256), 0, stream,
                     x, pe, lpos, g1, be1, g2, be2, xn_b, q_b, xcatB, xn2_b);
  // 2. merged off / attn-logits / val
  hipLaunchKernelGGL(k_mm3, dim3(GM1,4), dim3(256), 0, stream,
                     q_b, xn_b, wb_off, b_off, b_attn, b_val, off_b, aw_b, vm_b, NT1);
  // 3. fused softmax + deformable sampling
  hipLaunchKernelGGL(k_sample, dim3((NT1*H_+255)/256), dim3(256), 0, stream,
                     off_b, aw_b, refp, vm_b, o_b);
  // 4. out-proj1 + residual + LN2 -> xcat fp32 + xn2 bf16 (lv1..4)
  hipLaunchKernelGGL((k_mm<128,128,6>), dim3(GM1,1), dim3(256), 0, stream,
                     o_b, wb_wout, b_out, nullptr, xcatB, xn2_b, x, g2, be2, NT1);
  // 5. qkv (bf16, panel-looped: A staged once)
  hipLaunchKernelGGL((k_mmp<3,5>), dim3(GM2), dim3(256), 0, stream,
                     xn2_b, wb_in, in_b, qkv_b, NT2);
  // 6. MFMA flash attention v8 (register-direct PV)
  hipLaunchKernelGGL(k_attn7, dim3(B_*T_*4), dim3(128), 0, stream, qkv_b, ca_b);
  // 7. out-proj2 + residual + LN3 -> xcat fp32 (in place) + ln3 bf16
  hipLaunchKernelGGL((k_mm<128,128,7>), dim3(GM2,1), dim3(256), 0, stream,
                     ca_b, wb_outw, out_b, xcatB, xcatB, ln3_b, nullptr, g3, be3, NT2);
  // 8. FFN: fc1 (panel-looped) then fc2
  hipLaunchKernelGGL((k_mmp<4,4>), dim3(GM2), dim3(256), 0, stream,
                     ln3_b, wb_fc1, fc1_b, hid_b, NT2);
  hipLaunchKernelGGL((k_mm<512,128,3>), dim3(GM2,1), dim3(256), 0, stream,
                     hid_b, wb_fc2, fc2_b, xcatB, out, nullptr, nullptr, nullptr, nullptr, NT2);
}